// Round 7
// baseline (196.268 us; speedup 1.0000x reference)
//
#include <hip/hip_runtime.h>
#include <math.h>

// Problem constants (B=1)
#define TT   512
#define CEMB 768
#define NH   12
#define NKV  6
#define HD   64
#define KVC  (NKV*HD)   // 384
#define NTOT 1536       // q(768) | k(384) | v(384)
#define GP_STRIDE ((size_t)TT*NTOT)

// ---- fp32 GEMM partial: 64x64 tile, BK=16, 256 threads, 4x4 microtile ----
__device__ __forceinline__ void gemm_sk(const float* __restrict__ A,
                                        const float* __restrict__ B,
                                        float* __restrict__ P,
                                        int lda, int ldb, int ldc,
                                        int m0, int bcol, int pcol,
                                        int kbeg, int klen){
  __shared__ float As[2][16][68];
  __shared__ float Bs[2][16][68];
  int tid  = threadIdx.x;
  int arow = tid >> 2, ak4 = (tid & 3) * 4;
  int brow = tid >> 4, bc  = (tid & 15) * 4;
  int ty   = tid >> 4, tx = tid & 15;

  float acc[4][4];
  #pragma unroll
  for(int i=0;i<4;i++)
    #pragma unroll
    for(int j=0;j<4;j++) acc[i][j] = 0.f;

  const float* Ap = A + (size_t)(m0+arow)*lda + kbeg + ak4;
  const float* Bq = B + (size_t)(kbeg+brow)*ldb + bcol + bc;

  float4 a = *(const float4*)(Ap);
  float4 b = *(const float4*)(Bq);

  int buf = 0;
  for(int k0=0; k0<klen; k0+=16){
    As[buf][ak4+0][arow]=a.x; As[buf][ak4+1][arow]=a.y;
    As[buf][ak4+2][arow]=a.z; As[buf][ak4+3][arow]=a.w;
    *(float4*)&Bs[buf][brow][bc] = b;
    if (k0 + 16 < klen){
      a = *(const float4*)(Ap + k0 + 16);
      b = *(const float4*)(Bq + (size_t)(k0+16)*ldb);
    }
    __syncthreads();
    #pragma unroll
    for(int kk=0;kk<16;kk++){
      float4 av = *(float4*)&As[buf][kk][ty*4];
      float4 bv = *(float4*)&Bs[buf][kk][tx*4];
      #pragma unroll
      for(int r=0;r<4;r++)
        #pragma unroll
        for(int c=0;c<4;c++)
          acc[r][c] = fmaf((&av.x)[r], (&bv.x)[c], acc[r][c]);
    }
    buf ^= 1;
  }
  #pragma unroll
  for(int r=0;r<4;r++)
    *(float4*)(P + (size_t)(m0+ty*4+r)*ldc + pcol + tx*4) =
      make_float4(acc[r][0],acc[r][1],acc[r][2],acc[r][3]);
}

// merge 4 qkv split-K partials for one float4
__device__ __forceinline__ float4 load_merged(const float* __restrict__ P, int t, int col){
  size_t base = (size_t)t*NTOT + col;
  float4 a = *(const float4*)(P + base);
  float4 b = *(const float4*)(P + base + GP_STRIDE);
  float4 c = *(const float4*)(P + base + 2*GP_STRIDE);
  float4 d = *(const float4*)(P + base + 3*GP_STRIDE);
  return make_float4(a.x+b.x+c.x+d.x, a.y+b.y+c.y+d.y,
                     a.z+b.z+c.z+d.z, a.w+b.w+c.w+d.w);
}

// RoPE + RMSNorm over a 16-lane group holding one head-row (lane lc has d=lc*4..+3).
__device__ __forceinline__ float4 rope_rms4(float4 sum, int t, int lc,
    const float* __restrict__ cosb, const float* __restrict__ sinb){
  float4 prt;
  prt.x = __shfl_xor(sum.x, 8); prt.y = __shfl_xor(sum.y, 8);
  prt.z = __shfl_xor(sum.z, 8); prt.w = __shfl_xor(sum.w, 8);
  float4 cs = *(const float4*)(cosb + t*32 + (lc&7)*4);
  float4 sn = *(const float4*)(sinb + t*32 + (lc&7)*4);
  float4 rot;
  if (lc < 8){
    rot.x = sum.x*cs.x - prt.x*sn.x; rot.y = sum.y*cs.y - prt.y*sn.y;
    rot.z = sum.z*cs.z - prt.z*sn.z; rot.w = sum.w*cs.w - prt.w*sn.w;
  } else {
    rot.x = sum.x*cs.x + prt.x*sn.x; rot.y = sum.y*cs.y + prt.y*sn.y;
    rot.z = sum.z*cs.z + prt.z*sn.z; rot.w = sum.w*cs.w + prt.w*sn.w;
  }
  float ss = rot.x*rot.x + rot.y*rot.y + rot.z*rot.z + rot.w*rot.w;
  ss += __shfl_xor(ss,1); ss += __shfl_xor(ss,2);
  ss += __shfl_xor(ss,4); ss += __shfl_xor(ss,8);
  float sc = rsqrtf(ss*(1.0f/64.0f) + 1e-6f);
  rot.x*=sc; rot.y*=sc; rot.z*=sc; rot.w*=sc;
  return rot;
}

// K1: QKV split-K; last split block per tile merges + RoPE/RMS -> q,k,v.
__global__ void __launch_bounds__(256) gemm_qkv_fixup(const float* __restrict__ X,
    const float* __restrict__ Wq, const float* __restrict__ Wk, const float* __restrict__ Wv,
    float* __restrict__ P, unsigned* __restrict__ cnt,
    const float* __restrict__ cosb, const float* __restrict__ sinb,
    float* __restrict__ q, float* __restrict__ k, float* __restrict__ v){
  int mt = blockIdx.x;   // 0..7
  int nt = blockIdx.y;   // 0..23
  int ks = blockIdx.z;   // 0..3
  const float* B; int ldb, bcol;
  if (nt < 12)      { B = Wq; ldb = CEMB; bcol = nt*64; }
  else if (nt < 18) { B = Wk; ldb = KVC;  bcol = (nt-12)*64; }
  else              { B = Wv; ldb = KVC;  bcol = (nt-18)*64; }
  gemm_sk(X, B, P + (size_t)ks*GP_STRIDE, CEMB, ldb, NTOT,
          mt*64, bcol, nt*64, ks*192, 192);

  __shared__ int lastflag;
  __syncthreads();
  if (threadIdx.x == 0){
    __builtin_amdgcn_fence(__ATOMIC_RELEASE, "agent");
    unsigned old = __hip_atomic_fetch_add(&cnt[mt*24+nt], 1u,
                      __ATOMIC_RELAXED, __HIP_MEMORY_SCOPE_AGENT);
    lastflag = (old == 3u);
  }
  __syncthreads();
  if (lastflag){
    __builtin_amdgcn_fence(__ATOMIC_ACQUIRE, "agent");
    int g = threadIdx.x >> 4, lc = threadIdx.x & 15;
    #pragma unroll
    for(int pass=0; pass<4; ++pass){
      int t = mt*64 + pass*16 + g;
      float4 sum = load_merged(P, t, nt*64 + lc*4);
      if (nt < 18){
        float4 val = rope_rms4(sum, t, lc, cosb, sinb);
        if (nt < 12) *(float4*)&q[(size_t)t*CEMB + nt*64 + lc*4] = val;
        else         *(float4*)&k[(size_t)t*KVC + (nt-12)*64 + lc*4] = val;
      } else {
        *(float4*)&v[(size_t)t*KVC + (nt-18)*64 + lc*4] = sum;
      }
    }
  }
}

// K2: tropical attention, one 64x64 KV-tile per block. Grid (36, NH):
// idx -> (qt, ct<=qt). Wave w owns q-rows qt*64 + w*16..+15; lane microtile
// 4 rows (lane>>4) x 4 cols (lane&15). QPsh (stride 68) holds Q during the
// score phase, then P (same wave-private rows). K/V stride 64 + XOR swizzle.
// Last chunk-block per (h,qt) merges partials -> ybuf.
__global__ void __launch_bounds__(256) attn_kernel(const float* __restrict__ qn,
    const float* __restrict__ kn, const float* __restrict__ vr,
    float* __restrict__ part_acc, float2* __restrict__ part_ml,
    unsigned* __restrict__ cnt, float* __restrict__ ybuf){
  __shared__ float QPsh[64*68];
  __shared__ float Ksh[64*64];
  __shared__ float Vsh[64*64];
  __shared__ int lastflag;

  int h   = blockIdx.y;
  int idx = blockIdx.x;          // 0..35
  int qt = 0, rem = idx;
  while (rem > qt){ rem -= (qt+1); ++qt; }
  int ct = rem;                  // 0..qt
  int t0 = ct*64;

  int kvh  = h >> 1;
  int w    = threadIdx.x >> 6;
  int lane = threadIdx.x & 63;
  int lg   = lane >> 4;
  int lc   = lane & 15;

  // stage Q (wave-private rows) and K/V (swizzled)
  #pragma unroll
  for(int sub=0; sub<4; ++sub){
    int rr = w*16 + sub*4 + lg;
    int sw = ((lc ^ (rr>>2)) & 15)*4;
    *(float4*)&QPsh[rr*68 + lc*4] =
      *(const float4*)&qn[(size_t)(qt*64+rr)*CEMB + h*HD + lc*4];
    *(float4*)&Ksh[rr*64 + sw] =
      *(const float4*)&kn[(size_t)(t0+rr)*KVC + kvh*HD + lc*4];
    *(float4*)&Vsh[rr*64 + sw] =
      *(const float4*)&vr[(size_t)(t0+rr)*KVC + kvh*HD + lc*4];
  }
  __syncthreads();

  // scores: s[r][c] = max_d q[row_r][d] + k[col_c][d]
  float s[4][4];
  #pragma unroll
  for(int r=0;r<4;r++)
    #pragma unroll
    for(int c=0;c<4;c++) s[r][c] = -INFINITY;

  #pragma unroll
  for(int dg=0; dg<16; ++dg){
    float4 k4[4], q4[4];
    int ksw = ((dg ^ lc)&15)*4;
    #pragma unroll
    for(int c=0;c<4;c++)
      k4[c] = *(const float4*)&Ksh[(lc*4+c)*64 + ksw];
    #pragma unroll
    for(int r=0;r<4;r++)
      q4[r] = *(const float4*)&QPsh[(w*16+lg*4+r)*68 + dg*4];
    #pragma unroll
    for(int r=0;r<4;r++)
      #pragma unroll
      for(int c=0;c<4;c++)
        s[r][c] = fmaxf(s[r][c],
                  fmaxf(fmaxf(q4[r].x + k4[c].x, q4[r].y + k4[c].y),
                        fmaxf(q4[r].z + k4[c].z, q4[r].w + k4[c].w)));
  }

  // per-row tile softmax (single tile: no running state); P -> QPsh
  float mrow[4], lrow[4];
  #pragma unroll
  for(int r=0;r<4;r++){
    int i = qt*64 + w*16 + lg*4 + r;
    #pragma unroll
    for(int c=0;c<4;c++)
      if (t0 + lc*4 + c > i) s[r][c] = -INFINITY;   // causal mask
    float mt = fmaxf(fmaxf(s[r][0],s[r][1]), fmaxf(s[r][2],s[r][3]));
    mt = fmaxf(mt, __shfl_xor(mt,1));
    mt = fmaxf(mt, __shfl_xor(mt,2));
    mt = fmaxf(mt, __shfl_xor(mt,4));
    mt = fmaxf(mt, __shfl_xor(mt,8));
    float p0 = __expf(s[r][0]-mt), p1 = __expf(s[r][1]-mt);
    float p2 = __expf(s[r][2]-mt), p3 = __expf(s[r][3]-mt);
    float ps = p0+p1+p2+p3;
    ps += __shfl_xor(ps,1); ps += __shfl_xor(ps,2);
    ps += __shfl_xor(ps,4); ps += __shfl_xor(ps,8);
    mrow[r] = mt; lrow[r] = ps;
    *(float4*)&QPsh[(w*16+lg*4+r)*68 + lc*4] = make_float4(p0,p1,p2,p3);
  }
  __builtin_amdgcn_wave_barrier();   // DS in-order per wave; rows wave-private

  // PV: acc[r][c] = sum_j P[row_r][j] * V[j][col_c]
  float acc[4][4];
  #pragma unroll
  for(int r=0;r<4;r++)
    #pragma unroll
    for(int c=0;c<4;c++) acc[r][c] = 0.f;

  #pragma unroll
  for(int jg=0; jg<16; ++jg){
    float4 v4[4], p4[4];
    int vsw = ((lc ^ jg)&15)*4;
    #pragma unroll
    for(int jj=0;jj<4;jj++)
      v4[jj] = *(const float4*)&Vsh[(jg*4+jj)*64 + vsw];
    #pragma unroll
    for(int r=0;r<4;r++)
      p4[r] = *(const float4*)&QPsh[(w*16+lg*4+r)*68 + jg*4];
    #pragma unroll
    for(int r=0;r<4;r++)
      #pragma unroll
      for(int c=0;c<4;c++)
        acc[r][c] = fmaf(p4[r].x, (&v4[0].x)[c], fmaf(p4[r].y, (&v4[1].x)[c],
                    fmaf(p4[r].z, (&v4[2].x)[c], fmaf(p4[r].w, (&v4[3].x)[c], acc[r][c]))));
  }

  // write chunk partials
  #pragma unroll
  for(int r=0;r<4;r++){
    int i = qt*64 + w*16 + lg*4 + r;
    int pidx = (h*TT + i)*8 + ct;
    *(float4*)&part_acc[(size_t)pidx*64 + lc*4] =
      make_float4(acc[r][0],acc[r][1],acc[r][2],acc[r][3]);
    if (lc == 0) part_ml[pidx] = make_float2(mrow[r], lrow[r]);
  }

  // fixup: last chunk-block per (h,qt) merges -> ybuf
  __syncthreads();
  if (threadIdx.x == 0){
    __builtin_amdgcn_fence(__ATOMIC_RELEASE, "agent");
    unsigned old = __hip_atomic_fetch_add(&cnt[192 + h*8 + qt], 1u,
                      __ATOMIC_RELAXED, __HIP_MEMORY_SCOPE_AGENT);
    lastflag = (old == (unsigned)qt);
  }
  __syncthreads();
  if (lastflag){
    __builtin_amdgcn_fence(__ATOMIC_ACQUIRE, "agent");
    int g = threadIdx.x >> 4, lc2 = threadIdx.x & 15;
    #pragma unroll
    for(int pass=0; pass<4; ++pass){
      int i = qt*64 + pass*16 + g;
      float m = -INFINITY, l = 0.f;
      float ax=0.f, ay=0.f, az=0.f, aw=0.f;
      for(int c=0;c<=qt;c++){
        int pidx = (h*TT + i)*8 + c;
        float2 ml = part_ml[pidx];
        float4 ac = *(const float4*)&part_acc[(size_t)pidx*64 + lc2*4];
        float mn = fmaxf(m, ml.x);
        float sa = __expf(m - mn);
        float sc = __expf(ml.x - mn);
        l  = l*sa  + ml.y*sc;
        ax = ax*sa + ac.x*sc; ay = ay*sa + ac.y*sc;
        az = az*sa + ac.z*sc; aw = aw*sa + ac.w*sc;
        m = mn;
      }
      float inv = 1.0f / l;
      *(float4*)&ybuf[(size_t)i*CEMB + h*HD + lc2*4] =
        make_float4(ax*inv, ay*inv, az*inv, aw*inv);
    }
  }
}

// K3: proj split-K + fixup merge -> out
__global__ void __launch_bounds__(256) gemm_proj_fixup(const float* __restrict__ Y,
    const float* __restrict__ Wp, float* __restrict__ P,
    unsigned* __restrict__ cnt, float* __restrict__ out){
  gemm_sk(Y, Wp, P + (size_t)blockIdx.z*TT*CEMB, CEMB, CEMB, CEMB,
          blockIdx.x*64, blockIdx.y*64, blockIdx.y*64, blockIdx.z*192, 192);
  __shared__ int lastflag;
  __syncthreads();
  if (threadIdx.x == 0){
    __builtin_amdgcn_fence(__ATOMIC_RELEASE, "agent");
    unsigned old = __hip_atomic_fetch_add(&cnt[288 + blockIdx.y*8 + blockIdx.x], 1u,
                      __ATOMIC_RELAXED, __HIP_MEMORY_SCOPE_AGENT);
    lastflag = (old == 3u);
  }
  __syncthreads();
  if (lastflag){
    __builtin_amdgcn_fence(__ATOMIC_ACQUIRE, "agent");
    int ty = threadIdx.x >> 4, tx = threadIdx.x & 15;
    int m0 = blockIdx.x*64, n0 = blockIdx.y*64;
    #pragma unroll
    for(int r=0;r<4;r++){
      size_t off = (size_t)(m0+ty*4+r)*CEMB + n0 + tx*4;
      float4 a = *(const float4*)(P + off);
      float4 b = *(const float4*)(P + off + (size_t)TT*CEMB);
      float4 c = *(const float4*)(P + off + (size_t)2*TT*CEMB);
      float4 d = *(const float4*)(P + off + (size_t)3*TT*CEMB);
      *(float4*)(out + off) = make_float4(a.x+b.x+c.x+d.x, a.y+b.y+c.y+d.y,
                                          a.z+b.z+c.z+d.z, a.w+b.w+c.w+d.w);
    }
  }
}

extern "C" void kernel_launch(void* const* d_in, const int* in_sizes, int n_in,
                              void* d_out, int out_size, void* d_ws, size_t ws_size,
                              hipStream_t stream){
  const float* x    = (const float*)d_in[0];
  const float* cosb = (const float*)d_in[1];
  const float* sinb = (const float*)d_in[2];
  const float* Wq   = (const float*)d_in[3];
  const float* Wk   = (const float*)d_in[4];
  const float* Wv   = (const float*)d_in[5];
  const float* Wp   = (const float*)d_in[6];
  float* out = (float*)d_out;

  float* ws        = (float*)d_ws;
  float* gpart     = ws;                               // 4*512*1536 (qkv; reused by proj)
  float* q_raw     = gpart + 4*GP_STRIDE;              // 512*768
  float* k_raw     = q_raw + (size_t)TT*CEMB;          // 512*384
  float* v_raw     = k_raw + (size_t)TT*KVC;           // 512*384
  float* ybuf      = v_raw + (size_t)TT*KVC;           // 512*768
  float* part_acc  = ybuf + (size_t)TT*CEMB;           // 12*512*8*64
  float2* part_ml  = (float2*)(part_acc + (size_t)NH*TT*8*64);  // 12*512*8
  unsigned* cnt    = (unsigned*)(part_ml + (size_t)NH*TT*8);    // 384 counters

  hipMemsetAsync(cnt, 0, 384*sizeof(unsigned), stream);
  gemm_qkv_fixup <<<dim3(8,24,4), 256, 0, stream>>>(x, Wq, Wk, Wv, gpart, cnt,
                                                    cosb, sinb, q_raw, k_raw, v_raw);
  attn_kernel    <<<dim3(36,NH),  256, 0, stream>>>(q_raw, k_raw, v_raw,
                                                    part_acc, part_ml, cnt, ybuf);
  gemm_proj_fixup<<<dim3(8,12,4), 256, 0, stream>>>(ybuf, Wp, gpart, cnt, out);
}

// Round 8
// 135.729 us; speedup vs baseline: 1.4460x; 1.4460x over previous
//
#include <hip/hip_runtime.h>
#include <math.h>

// Problem constants (B=1)
#define TT   512
#define CEMB 768
#define NH   12
#define NKV  6
#define HD   64
#define KVC  (NKV*HD)   // 384
#define NTOT 1536       // q(768) | k(384) | v(384)
#define GP_STRIDE ((size_t)TT*NTOT)

__device__ __forceinline__ float wave_sum(float v){
  #pragma unroll
  for(int o=32;o>0;o>>=1) v += __shfl_xor(v, o);
  return v;
}

// ---- fp32 GEMM partial: 64x64 tile, BK=16, 256 threads, 4x4 microtile ----
// Split-K: accumulates A[m0:m0+64, kbeg:kbeg+klen] @ B into per-split partials.
// NO atomics, NO fences — merges happen in separate tiny kernels (R5-proven).
__device__ __forceinline__ void gemm_sk(const float* __restrict__ A,
                                        const float* __restrict__ B,
                                        float* __restrict__ P,
                                        int lda, int ldb, int ldc,
                                        int m0, int bcol, int pcol,
                                        int kbeg, int klen){
  __shared__ float As[2][16][68];
  __shared__ float Bs[2][16][68];
  int tid  = threadIdx.x;
  int arow = tid >> 2, ak4 = (tid & 3) * 4;
  int brow = tid >> 4, bc  = (tid & 15) * 4;
  int ty   = tid >> 4, tx = tid & 15;

  float acc[4][4];
  #pragma unroll
  for(int i=0;i<4;i++)
    #pragma unroll
    for(int j=0;j<4;j++) acc[i][j] = 0.f;

  const float* Ap = A + (size_t)(m0+arow)*lda + kbeg + ak4;
  const float* Bq = B + (size_t)(kbeg+brow)*ldb + bcol + bc;

  float4 a = *(const float4*)(Ap);
  float4 b = *(const float4*)(Bq);

  int buf = 0;
  for(int k0=0; k0<klen; k0+=16){
    As[buf][ak4+0][arow]=a.x; As[buf][ak4+1][arow]=a.y;
    As[buf][ak4+2][arow]=a.z; As[buf][ak4+3][arow]=a.w;
    *(float4*)&Bs[buf][brow][bc] = b;
    if (k0 + 16 < klen){
      a = *(const float4*)(Ap + k0 + 16);
      b = *(const float4*)(Bq + (size_t)(k0+16)*ldb);
    }
    __syncthreads();
    #pragma unroll
    for(int kk=0;kk<16;kk++){
      float4 av = *(float4*)&As[buf][kk][ty*4];
      float4 bv = *(float4*)&Bs[buf][kk][tx*4];
      #pragma unroll
      for(int r=0;r<4;r++)
        #pragma unroll
        for(int c=0;c<4;c++)
          acc[r][c] = fmaf((&av.x)[r], (&bv.x)[c], acc[r][c]);
    }
    buf ^= 1;
  }
  #pragma unroll
  for(int r=0;r<4;r++)
    *(float4*)(P + (size_t)(m0+ty*4+r)*ldc + pcol + tx*4) =
      make_float4(acc[r][0],acc[r][1],acc[r][2],acc[r][3]);
}

// K1: QKV split-K partials. splitK=4 (K=192 each).
__global__ void __launch_bounds__(256) gemm_qkv_partial(const float* __restrict__ X,
    const float* __restrict__ Wq, const float* __restrict__ Wk, const float* __restrict__ Wv,
    float* __restrict__ P){
  int mt = blockIdx.x;   // 0..7
  int nt = blockIdx.y;   // 0..23
  int ks = blockIdx.z;   // 0..3
  const float* B; int ldb, bcol;
  if (nt < 12)      { B = Wq; ldb = CEMB; bcol = nt*64; }
  else if (nt < 18) { B = Wk; ldb = KVC;  bcol = (nt-12)*64; }
  else              { B = Wv; ldb = KVC;  bcol = (nt-18)*64; }
  gemm_sk(X, B, P + (size_t)ks*GP_STRIDE, CEMB, ldb, NTOT,
          mt*64, bcol, nt*64, ks*192, 192);
}

// K5: proj split-K partials
__global__ void __launch_bounds__(256) gemm_proj_partial(const float* __restrict__ Y,
    const float* __restrict__ Wp, float* __restrict__ P){
  gemm_sk(Y, Wp, P + (size_t)blockIdx.z*TT*CEMB, CEMB, CEMB, CEMB,
          blockIdx.x*64, blockIdx.y*64, blockIdx.y*64, blockIdx.z*192, 192);
}

// K2: merge 4 qkv partials + fused RoPE + RMSNorm. One wave per (t, 64-col slot).
// Slots 0..11 = q heads, 12..17 = k heads, 18..23 = v heads.
__global__ void __launch_bounds__(256) merge_qkv(const float* __restrict__ P,
    const float* __restrict__ cosb, const float* __restrict__ sinb,
    float* __restrict__ q, float* __restrict__ k, float* __restrict__ v){
  int wid  = (blockIdx.x * blockDim.x + threadIdx.x) >> 6;  // 0..12287
  int lane = threadIdx.x & 63;
  int t    = wid / 24;
  int slot = wid - t*24;
  size_t base = (size_t)t*NTOT + slot*64 + lane;
  float sum = P[base] + P[base + GP_STRIDE] +
              P[base + 2*GP_STRIDE] + P[base + 3*GP_STRIDE];
  if (slot < 18){
    float c = cosb[t*32 + (lane&31)];
    float s = sinb[t*32 + (lane&31)];
    float partner = __shfl_xor(sum, 32);
    float rot = (lane < 32) ? (sum*c - partner*s) : (sum*c + partner*s);
    float ss = wave_sum(rot*rot);
    float val = rot * rsqrtf(ss * (1.0f/64.0f) + 1e-6f);
    if (slot < 12) q[(size_t)t*CEMB + slot*64 + lane] = val;
    else           k[(size_t)t*KVC + (slot-12)*64 + lane] = val;
  } else {
    v[(size_t)t*KVC + (slot-18)*64 + lane] = sum;
  }
}

// K6: merge 4 proj partials -> out. float4 per thread.
__global__ void __launch_bounds__(256) merge_out(const float* __restrict__ P,
    float* __restrict__ out){
  int i = (blockIdx.x * blockDim.x + threadIdx.x) * 4;   // < 512*768
  float4 a = *(const float4*)(P + i);
  float4 b = *(const float4*)(P + i + (size_t)TT*CEMB);
  float4 c = *(const float4*)(P + i + (size_t)2*TT*CEMB);
  float4 d = *(const float4*)(P + i + (size_t)3*TT*CEMB);
  *(float4*)(out + i) = make_float4(a.x+b.x+c.x+d.x, a.y+b.y+c.y+d.y,
                                    a.z+b.z+c.z+d.z, a.w+b.w+c.w+d.w);
}

// K3: tropical attention, one 64x64 KV-tile per block. Grid (36, NH):
// idx -> (qt, ct<=qt), 432 uniform blocks. Wave w owns q-rows qt*64+w*16..+15;
// lane microtile 4 rows (lane>>4) x 4 cols (lane&15). QPsh (stride 68, 0-conflict
// measured) holds Q during scores then P (rows wave-private). K/V stride 64 +
// XOR swizzle (0-conflict measured). Single tile => no online-softmax state.
// NO fences/atomics; partials merged by attn_reduce.
__global__ void __launch_bounds__(256) attn_tile(const float* __restrict__ qn,
    const float* __restrict__ kn, const float* __restrict__ vr,
    float* __restrict__ part_acc, float2* __restrict__ part_ml){
  __shared__ float QPsh[64*68];
  __shared__ float Ksh[64*64];
  __shared__ float Vsh[64*64];

  int h   = blockIdx.y;
  int idx = blockIdx.x;          // 0..35
  int qt = 0, rem = idx;
  while (rem > qt){ rem -= (qt+1); ++qt; }
  int ct = rem;                  // 0..qt
  int t0 = ct*64;

  int kvh  = h >> 1;
  int w    = threadIdx.x >> 6;
  int lane = threadIdx.x & 63;
  int lg   = lane >> 4;
  int lc   = lane & 15;

  #pragma unroll
  for(int sub=0; sub<4; ++sub){
    int rr = w*16 + sub*4 + lg;
    int sw = ((lc ^ (rr>>2)) & 15)*4;
    *(float4*)&QPsh[rr*68 + lc*4] =
      *(const float4*)&qn[(size_t)(qt*64+rr)*CEMB + h*HD + lc*4];
    *(float4*)&Ksh[rr*64 + sw] =
      *(const float4*)&kn[(size_t)(t0+rr)*KVC + kvh*HD + lc*4];
    *(float4*)&Vsh[rr*64 + sw] =
      *(const float4*)&vr[(size_t)(t0+rr)*KVC + kvh*HD + lc*4];
  }
  __syncthreads();

  // scores: s[r][c] = max_d q[row_r][d] + k[col_c][d]
  float s[4][4];
  #pragma unroll
  for(int r=0;r<4;r++)
    #pragma unroll
    for(int c=0;c<4;c++) s[r][c] = -INFINITY;

  #pragma unroll
  for(int dg=0; dg<16; ++dg){
    float4 k4[4], q4[4];
    int ksw = ((dg ^ lc)&15)*4;
    #pragma unroll
    for(int c=0;c<4;c++)
      k4[c] = *(const float4*)&Ksh[(lc*4+c)*64 + ksw];
    #pragma unroll
    for(int r=0;r<4;r++)
      q4[r] = *(const float4*)&QPsh[(w*16+lg*4+r)*68 + dg*4];
    #pragma unroll
    for(int r=0;r<4;r++)
      #pragma unroll
      for(int c=0;c<4;c++)
        s[r][c] = fmaxf(s[r][c],
                  fmaxf(fmaxf(q4[r].x + k4[c].x, q4[r].y + k4[c].y),
                        fmaxf(q4[r].z + k4[c].z, q4[r].w + k4[c].w)));
  }

  // per-row tile softmax; P overwrites Q region (wave-private rows)
  float mrow[4], lrow[4];
  #pragma unroll
  for(int r=0;r<4;r++){
    int i = qt*64 + w*16 + lg*4 + r;
    #pragma unroll
    for(int c=0;c<4;c++)
      if (t0 + lc*4 + c > i) s[r][c] = -INFINITY;   // causal mask
    float mt = fmaxf(fmaxf(s[r][0],s[r][1]), fmaxf(s[r][2],s[r][3]));
    mt = fmaxf(mt, __shfl_xor(mt,1));
    mt = fmaxf(mt, __shfl_xor(mt,2));
    mt = fmaxf(mt, __shfl_xor(mt,4));
    mt = fmaxf(mt, __shfl_xor(mt,8));
    float p0 = __expf(s[r][0]-mt), p1 = __expf(s[r][1]-mt);
    float p2 = __expf(s[r][2]-mt), p3 = __expf(s[r][3]-mt);
    float ps = p0+p1+p2+p3;
    ps += __shfl_xor(ps,1); ps += __shfl_xor(ps,2);
    ps += __shfl_xor(ps,4); ps += __shfl_xor(ps,8);
    mrow[r] = mt; lrow[r] = ps;
    *(float4*)&QPsh[(w*16+lg*4+r)*68 + lc*4] = make_float4(p0,p1,p2,p3);
  }
  __builtin_amdgcn_wave_barrier();   // DS in-order per wave; rows wave-private

  // PV: acc[r][c] = sum_j P[row_r][j] * V[j][col_c]
  float acc[4][4];
  #pragma unroll
  for(int r=0;r<4;r++)
    #pragma unroll
    for(int c=0;c<4;c++) acc[r][c] = 0.f;

  #pragma unroll
  for(int jg=0; jg<16; ++jg){
    float4 v4[4], p4[4];
    int vsw = ((lc ^ jg)&15)*4;
    #pragma unroll
    for(int jj=0;jj<4;jj++)
      v4[jj] = *(const float4*)&Vsh[(jg*4+jj)*64 + vsw];
    #pragma unroll
    for(int r=0;r<4;r++)
      p4[r] = *(const float4*)&QPsh[(w*16+lg*4+r)*68 + jg*4];
    #pragma unroll
    for(int r=0;r<4;r++)
      #pragma unroll
      for(int c=0;c<4;c++)
        acc[r][c] = fmaf(p4[r].x, (&v4[0].x)[c], fmaf(p4[r].y, (&v4[1].x)[c],
                    fmaf(p4[r].z, (&v4[2].x)[c], fmaf(p4[r].w, (&v4[3].x)[c], acc[r][c]))));
  }

  // write chunk partials (stride 8 chunks per row)
  #pragma unroll
  for(int r=0;r<4;r++){
    int i = qt*64 + w*16 + lg*4 + r;
    int pidx = (h*TT + i)*8 + ct;
    *(float4*)&part_acc[(size_t)pidx*64 + lc*4] =
      make_float4(acc[r][0],acc[r][1],acc[r][2],acc[r][3]);
    if (lc == 0) part_ml[pidx] = make_float2(mrow[r], lrow[r]);
  }
}

// K4: merge <=8 chunk partials per (h, row). One wave per row.
__global__ void __launch_bounds__(256) attn_reduce(const float* __restrict__ part_acc,
    const float2* __restrict__ part_ml, float* __restrict__ y){
  int wid  = (blockIdx.x * blockDim.x + threadIdx.x) >> 6;  // 0..6143
  int lane = threadIdx.x & 63;
  int h = wid >> 9;
  int i = wid & 511;
  int nch = (i >> 6) + 1;
  float m = -INFINITY, l = 0.f, a = 0.f;
  for(int c=0;c<nch;c++){
    int pidx = (h*TT + i)*8 + c;
    float2 ml = part_ml[pidx];
    float ac  = part_acc[(size_t)pidx*64 + lane];
    float m_new = fmaxf(m, ml.x);
    float sa  = __expf(m - m_new);      // c=0: exp(-inf)=0
    float sc_ = __expf(ml.x - m_new);
    l = l*sa + ml.y*sc_;
    a = a*sa + ac*sc_;
    m = m_new;
  }
  y[(size_t)i*CEMB + h*HD + lane] = a / l;
}

extern "C" void kernel_launch(void* const* d_in, const int* in_sizes, int n_in,
                              void* d_out, int out_size, void* d_ws, size_t ws_size,
                              hipStream_t stream){
  const float* x    = (const float*)d_in[0];
  const float* cosb = (const float*)d_in[1];
  const float* sinb = (const float*)d_in[2];
  const float* Wq   = (const float*)d_in[3];
  const float* Wk   = (const float*)d_in[4];
  const float* Wv   = (const float*)d_in[5];
  const float* Wp   = (const float*)d_in[6];
  float* out = (float*)d_out;

  float* ws       = (float*)d_ws;
  float* gpart    = ws;                               // 4*512*1536 (qkv; reused by proj)
  float* q_raw    = gpart + 4*GP_STRIDE;              // 512*768
  float* k_raw    = q_raw + (size_t)TT*CEMB;          // 512*384
  float* v_raw    = k_raw + (size_t)TT*KVC;           // 512*384
  float* ybuf     = v_raw + (size_t)TT*KVC;           // 512*768
  float* part_acc = ybuf + (size_t)TT*CEMB;           // 12*512*8*64
  float2* part_ml = (float2*)(part_acc + (size_t)NH*TT*8*64);  // 12*512*8

  gemm_qkv_partial <<<dim3(8,24,4), 256, 0, stream>>>(x, Wq, Wk, Wv, gpart);
  merge_qkv        <<<dim3(3072),   256, 0, stream>>>(gpart, cosb, sinb, q_raw, k_raw, v_raw);
  attn_tile        <<<dim3(36,NH),  256, 0, stream>>>(q_raw, k_raw, v_raw, part_acc, part_ml);
  attn_reduce      <<<dim3(NH*TT/4),256, 0, stream>>>(part_acc, part_ml, ybuf);
  gemm_proj_partial<<<dim3(8,12,4), 256, 0, stream>>>(ybuf, Wp, gpart);
  merge_out        <<<dim3(TT*CEMB/1024), 256, 0, stream>>>(gpart, out);
}

// Round 9
// 120.926 us; speedup vs baseline: 1.6230x; 1.1224x over previous
//
#include <hip/hip_runtime.h>
#include <hip/hip_bf16.h>
#include <math.h>

// Problem constants (B=1)
#define TT   512
#define CEMB 768
#define NH   12
#define NKV  6
#define HD   64
#define KVC  (NKV*HD)   // 384

typedef short short8 __attribute__((ext_vector_type(8)));
typedef float floatx4 __attribute__((ext_vector_type(4)));

// fp32 pair -> packed bf16 (round-to-nearest via HW packed convert)
__device__ __forceinline__ unsigned pack_bf16(float lo, float hi){
  __hip_bfloat162 h = __float22bfloat162_rn(make_float2(lo, hi));
  return *reinterpret_cast<unsigned*>(&h);
}
__device__ __forceinline__ unsigned short bf16_rn(float f){
  unsigned u = __float_as_uint(f);
  u += 0x7FFFu + ((u>>16)&1u);
  return (unsigned short)(u>>16);
}

// ============================================================================
// K1: QKV GEMM via bf16 MFMA (no split-K) + block-local RoPE/RMS epilogue.
// Grid x: 0..191 = gemm tiles (mt=bx/24 of 8, nt=bx%24 of 24), 192..227 = 36
// blocks packing Wp (768x768 fp32) into bf16 B-fragment layout for K4.
// Block: 256 thr / 4 waves; C tile 64x64; wave strip 16x64; BK=32 dbuf LDS.
// MFMA layouts (guide §3, m89/m120-verified): a_frag A[m=lane&15][k=q*8+j],
// b_frag B[k=q*8+j][n=lane&15], D col=lane&15 row=q*4+reg.
// ============================================================================
__global__ void __launch_bounds__(256) gemm_qkv_mfma(
    const float* __restrict__ X,
    const float* __restrict__ Wq, const float* __restrict__ Wk, const float* __restrict__ Wv,
    const float* __restrict__ Wp,
    const float* __restrict__ cosb, const float* __restrict__ sinb,
    float* __restrict__ q, float* __restrict__ k, float* __restrict__ v,
    unsigned short* __restrict__ WpF){
  int bx = blockIdx.x;
  if (bx >= 192){
    // ---- Wp -> fragment-layout bf16 (producer for K4; rides free on idle CUs)
    // WpF[(ct 0..47)][(ks 0..23)][lane 0..63][j 0..7], elem = Wp[ks*32+q*8+j][ct*16+r]
    int t0 = (bx-192)*256 + threadIdx.x;           // 0..9215
    for(int g=0; g<8; ++g){
      int u  = g*9216 + t0;                        // 0..73727
      int kp = u / 192;                            // k-pair 0..383
      int n4 = (u - kp*192)*4;                     // col base
      int kk = kp*2;
      float4 w0 = *(const float4*)&Wp[(size_t)kk*CEMB + n4];
      float4 w1 = *(const float4*)&Wp[(size_t)(kk+1)*CEMB + n4];
      int ks = kk>>5, qq = (kk>>3)&3, j = kk&7;    // j even
      #pragma unroll
      for(int i=0;i<4;i++){
        int n = n4+i, ct = n>>4, r = n&15;
        *(unsigned*)&WpF[ (((size_t)(ct*24 + ks)*64 + qq*16 + r)<<3) + j ] =
          pack_bf16((&w0.x)[i], (&w1.x)[i]);
      }
    }
    return;
  }
  // ---- GEMM part
  int mt = bx / 24, nt = bx % 24;
  const float* W; int ldb, bcol;
  if (nt < 12)      { W = Wq; ldb = CEMB; bcol = nt*64; }
  else if (nt < 18) { W = Wk; ldb = KVC;  bcol = (nt-12)*64; }
  else              { W = Wv; ldb = KVC;  bcol = (nt-18)*64; }

  // [m or n][k] bf16, row stride 40 shorts (80 B: 16B-aligned b128 frags)
  __shared__ __align__(16) unsigned short Al[2][64][40];
  __shared__ __align__(16) unsigned short Bl[2][64][40];

  int tid = threadIdx.x;
  int am  = tid>>2,  akg = (tid&3)*8;    // A stage: row, k-group of 8
  int bkp = tid>>4,  bn4 = (tid&15)*4;   // B stage: k-pair, 4 cols
  int w = tid>>6, lane = tid&63, qq = lane>>4, r = lane&15;

  floatx4 acc[4];
  #pragma unroll
  for(int c=0;c<4;c++) acc[c] = (floatx4){0.f,0.f,0.f,0.f};

  const float* Ap = X + (size_t)(mt*64 + am)*CEMB + akg;
  const float* Bp = W + (size_t)(2*bkp)*ldb + bcol + bn4;

  float4 a0 = *(const float4*)(Ap);
  float4 a1 = *(const float4*)(Ap + 4);
  float4 b0 = *(const float4*)(Bp);
  float4 b1 = *(const float4*)(Bp + ldb);

  int buf = 0;
  for(int k0=0; k0<CEMB; k0+=32){
    unsigned p0 = pack_bf16(a0.x,a0.y), p1 = pack_bf16(a0.z,a0.w);
    unsigned p2 = pack_bf16(a1.x,a1.y), p3 = pack_bf16(a1.z,a1.w);
    *(uint4*)&Al[buf][am][akg] = make_uint4(p0,p1,p2,p3);
    #pragma unroll
    for(int i=0;i<4;i++)
      *(unsigned*)&Bl[buf][bn4+i][2*bkp] = pack_bf16((&b0.x)[i], (&b1.x)[i]);
    if (k0 + 32 < CEMB){
      a0 = *(const float4*)(Ap + k0+32);
      a1 = *(const float4*)(Ap + k0+36);
      b0 = *(const float4*)(Bp + (size_t)(k0+32)*ldb);
      b1 = *(const float4*)(Bp + (size_t)(k0+33)*ldb);
    }
    __syncthreads();
    short8 af = *(short8*)&Al[buf][w*16 + r][qq*8];
    #pragma unroll
    for(int c=0;c<4;c++){
      short8 bf = *(short8*)&Bl[buf][c*16 + r][qq*8];
      acc[c] = __builtin_amdgcn_mfma_f32_16x16x32_bf16(af, bf, acc[c], 0,0,0);
    }
    buf ^= 1;
  }

  // epilogue: rows t = mt*64+w*16+qq*4+reg; lane r holds cols {c*16+r}.
  // RoPE pairs d<->d+32 are c<->c+2 (same lane). RMS over quad (16 lanes x 4c).
  #pragma unroll
  for(int reg=0; reg<4; ++reg){
    int t = mt*64 + w*16 + qq*4 + reg;
    if (nt < 18){
      float cs0 = cosb[t*32 + r],      sn0 = sinb[t*32 + r];
      float cs1 = cosb[t*32 + 16 + r], sn1 = sinb[t*32 + 16 + r];
      float x0 = acc[0][reg], x1 = acc[1][reg], x2 = acc[2][reg], x3 = acc[3][reg];
      float n0 = x0*cs0 - x2*sn0;
      float n1 = x1*cs1 - x3*sn1;
      float n2 = x2*cs0 + x0*sn0;
      float n3 = x3*cs1 + x1*sn1;
      float ss = n0*n0 + n1*n1 + n2*n2 + n3*n3;
      ss += __shfl_xor(ss,1); ss += __shfl_xor(ss,2);
      ss += __shfl_xor(ss,4); ss += __shfl_xor(ss,8);
      float sc = rsqrtf(ss*(1.0f/64.0f) + 1e-6f);
      float* dst = (nt < 12) ? (q + (size_t)t*CEMB + nt*64)
                             : (k + (size_t)t*KVC + (nt-12)*64);
      dst[r]    = n0*sc; dst[16+r] = n1*sc;
      dst[32+r] = n2*sc; dst[48+r] = n3*sc;
    } else {
      float* dst = v + (size_t)t*KVC + (nt-18)*64;
      dst[r]    = acc[0][reg]; dst[16+r] = acc[1][reg];
      dst[32+r] = acc[2][reg]; dst[48+r] = acc[3][reg];
    }
  }
}

// ============================================================================
// K2: tropical attention, one 64x64 KV-tile per block (R8-proven, unchanged).
// ============================================================================
__global__ void __launch_bounds__(256) attn_tile(const float* __restrict__ qn,
    const float* __restrict__ kn, const float* __restrict__ vr,
    float* __restrict__ part_acc, float2* __restrict__ part_ml){
  __shared__ float QPsh[64*68];
  __shared__ float Ksh[64*64];
  __shared__ float Vsh[64*64];

  int h   = blockIdx.y;
  int idx = blockIdx.x;          // 0..35
  int qt = 0, rem = idx;
  while (rem > qt){ rem -= (qt+1); ++qt; }
  int ct = rem;                  // 0..qt
  int t0 = ct*64;

  int kvh  = h >> 1;
  int w    = threadIdx.x >> 6;
  int lane = threadIdx.x & 63;
  int lg   = lane >> 4;
  int lc   = lane & 15;

  #pragma unroll
  for(int sub=0; sub<4; ++sub){
    int rr = w*16 + sub*4 + lg;
    int sw = ((lc ^ (rr>>2)) & 15)*4;
    *(float4*)&QPsh[rr*68 + lc*4] =
      *(const float4*)&qn[(size_t)(qt*64+rr)*CEMB + h*HD + lc*4];
    *(float4*)&Ksh[rr*64 + sw] =
      *(const float4*)&kn[(size_t)(t0+rr)*KVC + kvh*HD + lc*4];
    *(float4*)&Vsh[rr*64 + sw] =
      *(const float4*)&vr[(size_t)(t0+rr)*KVC + kvh*HD + lc*4];
  }
  __syncthreads();

  float s[4][4];
  #pragma unroll
  for(int r=0;r<4;r++)
    #pragma unroll
    for(int c=0;c<4;c++) s[r][c] = -INFINITY;

  #pragma unroll
  for(int dg=0; dg<16; ++dg){
    float4 k4[4], q4[4];
    int ksw = ((dg ^ lc)&15)*4;
    #pragma unroll
    for(int c=0;c<4;c++)
      k4[c] = *(const float4*)&Ksh[(lc*4+c)*64 + ksw];
    #pragma unroll
    for(int r=0;r<4;r++)
      q4[r] = *(const float4*)&QPsh[(w*16+lg*4+r)*68 + dg*4];
    #pragma unroll
    for(int r=0;r<4;r++)
      #pragma unroll
      for(int c=0;c<4;c++)
        s[r][c] = fmaxf(s[r][c],
                  fmaxf(fmaxf(q4[r].x + k4[c].x, q4[r].y + k4[c].y),
                        fmaxf(q4[r].z + k4[c].z, q4[r].w + k4[c].w)));
  }

  float mrow[4], lrow[4];
  #pragma unroll
  for(int r=0;r<4;r++){
    int i = qt*64 + w*16 + lg*4 + r;
    #pragma unroll
    for(int c=0;c<4;c++)
      if (t0 + lc*4 + c > i) s[r][c] = -INFINITY;   // causal mask
    float mt = fmaxf(fmaxf(s[r][0],s[r][1]), fmaxf(s[r][2],s[r][3]));
    mt = fmaxf(mt, __shfl_xor(mt,1));
    mt = fmaxf(mt, __shfl_xor(mt,2));
    mt = fmaxf(mt, __shfl_xor(mt,4));
    mt = fmaxf(mt, __shfl_xor(mt,8));
    float p0 = __expf(s[r][0]-mt), p1 = __expf(s[r][1]-mt);
    float p2 = __expf(s[r][2]-mt), p3 = __expf(s[r][3]-mt);
    float ps = p0+p1+p2+p3;
    ps += __shfl_xor(ps,1); ps += __shfl_xor(ps,2);
    ps += __shfl_xor(ps,4); ps += __shfl_xor(ps,8);
    mrow[r] = mt; lrow[r] = ps;
    *(float4*)&QPsh[(w*16+lg*4+r)*68 + lc*4] = make_float4(p0,p1,p2,p3);
  }
  __builtin_amdgcn_wave_barrier();   // DS in-order per wave; rows wave-private

  float acc[4][4];
  #pragma unroll
  for(int r=0;r<4;r++)
    #pragma unroll
    for(int c=0;c<4;c++) acc[r][c] = 0.f;

  #pragma unroll
  for(int jg=0; jg<16; ++jg){
    float4 v4[4], p4[4];
    int vsw = ((lc ^ jg)&15)*4;
    #pragma unroll
    for(int jj=0;jj<4;jj++)
      v4[jj] = *(const float4*)&Vsh[(jg*4+jj)*64 + vsw];
    #pragma unroll
    for(int r=0;r<4;r++)
      p4[r] = *(const float4*)&QPsh[(w*16+lg*4+r)*68 + jg*4];
    #pragma unroll
    for(int r=0;r<4;r++)
      #pragma unroll
      for(int c=0;c<4;c++)
        acc[r][c] = fmaf(p4[r].x, (&v4[0].x)[c], fmaf(p4[r].y, (&v4[1].x)[c],
                    fmaf(p4[r].z, (&v4[2].x)[c], fmaf(p4[r].w, (&v4[3].x)[c], acc[r][c]))));
  }

  #pragma unroll
  for(int r=0;r<4;r++){
    int i = qt*64 + w*16 + lg*4 + r;
    int pidx = (h*TT + i)*8 + ct;
    *(float4*)&part_acc[(size_t)pidx*64 + lc*4] =
      make_float4(acc[r][0],acc[r][1],acc[r][2],acc[r][3]);
    if (lc == 0) part_ml[pidx] = make_float2(mrow[r], lrow[r]);
  }
}

// ============================================================================
// K3: merge <=8 chunk partials per (h,row); emit y as bf16 A-fragment layout
// for K4 (producer-side: each element written exactly once).
// yF[(s 0..31)][(ks 0..23)][lane][j]: elem = y[s*16+r][ks*32+q*8+j]
// ============================================================================
__global__ void __launch_bounds__(256) attn_reduce(const float* __restrict__ part_acc,
    const float2* __restrict__ part_ml, unsigned short* __restrict__ yF){
  int wid  = (blockIdx.x * blockDim.x + threadIdx.x) >> 6;  // 0..6143
  int lane = threadIdx.x & 63;
  int h = wid >> 9;
  int i = wid & 511;
  int nch = (i >> 6) + 1;
  float m = -INFINITY, l = 0.f, a = 0.f;
  for(int c=0;c<nch;c++){
    int pidx = (h*TT + i)*8 + c;
    float2 ml = part_ml[pidx];
    float ac  = part_acc[(size_t)pidx*64 + lane];
    float m_new = fmaxf(m, ml.x);
    float sa  = __expf(m - m_new);
    float sc_ = __expf(ml.x - m_new);
    l = l*sa + ml.y*sc_;
    a = a*sa + ac*sc_;
    m = m_new;
  }
  float val = a / l;
  int s = i>>4, rr = i&15;
  int ks = h*2 + (lane>>5), q2 = (lane>>3)&3, j = lane&7;
  yF[ (((size_t)(s*24 + ks)*64 + q2*16 + rr)<<3) + j ] = bf16_rn(val);
}

// ============================================================================
// K4: proj GEMM, fragment-direct (no LDS, no barriers). 96 blocks (8mt x 12nt),
// 4 waves, wave strip 16x64. a/b frags are linear 1KB-per-wave global loads
// from the pre-packed yF / WpF buffers (L2-resident). 1-step reg prefetch.
// ============================================================================
__global__ void __launch_bounds__(256) gemm_proj_mfma(
    const unsigned short* __restrict__ yF, const unsigned short* __restrict__ WpF,
    float* __restrict__ out){
  int bx = blockIdx.x;
  int mt = bx / 12, nt = bx % 12;
  int tid = threadIdx.x, w = tid>>6, lane = tid&63, qq = lane>>4, r = lane&15;
  int s = mt*4 + w;   // 16-row strip

  const short8* Af = (const short8*)yF  + (size_t)s*24*64 + lane;
  const short8* Bf = (const short8*)WpF + lane;

  floatx4 acc[4];
  #pragma unroll
  for(int c=0;c<4;c++) acc[c] = (floatx4){0.f,0.f,0.f,0.f};

  short8 ac_ = Af[0];
  short8 bc_[4];
  #pragma unroll
  for(int c=0;c<4;c++) bc_[c] = Bf[(size_t)((nt*4+c)*24)*64];

  for(int ks=0; ks<24; ++ks){
    short8 an; short8 bn[4];
    if (ks < 23){
      an = Af[(size_t)(ks+1)*64];
      #pragma unroll
      for(int c=0;c<4;c++) bn[c] = Bf[(size_t)((nt*4+c)*24 + ks+1)*64];
    }
    #pragma unroll
    for(int c=0;c<4;c++)
      acc[c] = __builtin_amdgcn_mfma_f32_16x16x32_bf16(ac_, bc_[c], acc[c], 0,0,0);
    if (ks < 23){
      ac_ = an;
      #pragma unroll
      for(int c=0;c<4;c++) bc_[c] = bn[c];
    }
  }

  #pragma unroll
  for(int reg=0; reg<4; ++reg){
    int t = mt*64 + w*16 + qq*4 + reg;
    float* dst = out + (size_t)t*CEMB + nt*64;
    #pragma unroll
    for(int c=0;c<4;c++)
      dst[c*16 + r] = acc[c][reg];
  }
}

extern "C" void kernel_launch(void* const* d_in, const int* in_sizes, int n_in,
                              void* d_out, int out_size, void* d_ws, size_t ws_size,
                              hipStream_t stream){
  const float* x    = (const float*)d_in[0];
  const float* cosb = (const float*)d_in[1];
  const float* sinb = (const float*)d_in[2];
  const float* Wq   = (const float*)d_in[3];
  const float* Wk   = (const float*)d_in[4];
  const float* Wv   = (const float*)d_in[5];
  const float* Wp   = (const float*)d_in[6];
  float* out = (float*)d_out;

  float* ws        = (float*)d_ws;
  float* q_raw     = ws;                                // 512*768
  float* k_raw     = q_raw + (size_t)TT*CEMB;           // 512*384
  float* v_raw     = k_raw + (size_t)TT*KVC;            // 512*384
  float* part_acc  = v_raw + (size_t)TT*KVC;            // 12*512*8*64
  float2* part_ml  = (float2*)(part_acc + (size_t)NH*TT*8*64);  // 12*512*8
  unsigned short* WpF = (unsigned short*)(part_ml + (size_t)NH*TT*8); // 48*24*64*8
  unsigned short* yF  = WpF + (size_t)48*24*64*8;       // 32*24*64*8

  gemm_qkv_mfma <<<dim3(228),   256, 0, stream>>>(x, Wq, Wk, Wv, Wp, cosb, sinb,
                                                  q_raw, k_raw, v_raw, WpF);
  attn_tile     <<<dim3(36,NH), 256, 0, stream>>>(q_raw, k_raw, v_raw, part_acc, part_ml);
  attn_reduce   <<<dim3(NH*TT/4), 256, 0, stream>>>(part_acc, part_ml, yF);
  gemm_proj_mfma<<<dim3(96),    256, 0, stream>>>(yF, WpF, out);
}